// Round 10
// baseline (1284.506 us; speedup 1.0000x reference)
//
#include <hip/hip_runtime.h>
#include <hip/hip_bf16.h>
#include <math.h>

// Problem constants
#define B_ 4
#define L_ 512
#define DM 768
#define E_ 1536
#define N_ 16
#define R_ 48
#define K_ 4
#define NL_ 4
#define H_ 1536
#define T_ 28
#define BT_ (B_ * L_)   // 2048 tokens
#define PJ 80           // R_ + 2*N_

typedef __bf16 bf16x8 __attribute__((ext_vector_type(8)));
typedef float  f32x4  __attribute__((ext_vector_type(4)));

__device__ __forceinline__ float sigmoidf_(float v) { return 1.0f / (1.0f + expf(-v)); }
__device__ __forceinline__ float siluf_(float v) { return v * sigmoidf_(v); }
__device__ __forceinline__ float softplusf_(float v) {
    return fmaxf(v, 0.0f) + log1pf(expf(-fabsf(v)));
}
__device__ __forceinline__ unsigned short f2bf(float x) {
    unsigned u = __float_as_uint(x);
    u = u + 0x7fffu + ((u >> 16) & 1u);
    return (unsigned short)(u >> 16);
}
__device__ __forceinline__ float bf2f(unsigned short h) {
    return __uint_as_float(((unsigned)h) << 16);
}
__device__ __forceinline__ void gl_lds16(const void* g, void* l) {
    auto gp = reinterpret_cast<const __attribute__((address_space(1))) unsigned int*>(
        reinterpret_cast<uintptr_t>(g));
    auto lp = reinterpret_cast<__attribute__((address_space(3))) unsigned int*>(
        reinterpret_cast<uintptr_t>(l));
    __builtin_amdgcn_global_load_lds(gp, lp, 16, 0, 0);
}

// ---------------- embed gather ----------------
__global__ __launch_bounds__(256) void k_embed(const int* __restrict__ ids,
                                               const float* __restrict__ embed,
                                               float* __restrict__ h) {
    int bt = blockIdx.x;
    int tok = ids[bt];
    const float* src = embed + (size_t)tok * DM;
    float* dst = h + (size_t)bt * DM;
    for (int c = threadIdx.x; c < DM; c += 256) dst[c] = src[c];
}

// ---------------- RMSNorm; BF=true emits bf16 hi/lo split ----------------
template <bool BF>
__global__ __launch_bounds__(256) void k_rmsnorm(const float* __restrict__ base, long rstride,
                                                 const float* __restrict__ w,
                                                 float* __restrict__ outf,
                                                 unsigned short* __restrict__ oh,
                                                 unsigned short* __restrict__ ol) {
    int tid = threadIdx.x;
    const float* row = base + (size_t)blockIdx.x * rstride;
    float v0 = row[tid], v1 = row[tid + 256], v2 = row[tid + 512];
    float s = v0 * v0 + v1 * v1 + v2 * v2;
#pragma unroll
    for (int m = 1; m < 64; m <<= 1) s += __shfl_xor(s, m);
    __shared__ float red[4];
    if ((tid & 63) == 0) red[tid >> 6] = s;
    __syncthreads();
    s = red[0] + red[1] + red[2] + red[3];
    float rs = rsqrtf(s * (1.0f / (float)DM) + 1e-5f);
    float r0 = v0 * rs * w[tid];
    float r1 = v1 * rs * w[tid + 256];
    float r2 = v2 * rs * w[tid + 512];
    size_t o = (size_t)blockIdx.x * DM;
    if (BF) {
        unsigned short h0 = f2bf(r0), h1 = f2bf(r1), h2 = f2bf(r2);
        oh[o + tid] = h0;        ol[o + tid] = f2bf(r0 - bf2f(h0));
        oh[o + tid + 256] = h1;  ol[o + tid + 256] = f2bf(r1 - bf2f(h1));
        oh[o + tid + 512] = h2;  ol[o + tid + 512] = f2bf(r2 - bf2f(h2));
    } else {
        outf[o + tid] = r0;
        outf[o + tid + 256] = r1;
        outf[o + tid + 512] = r2;
    }
}

// ---------------- weight transpose + split: w[K][N] -> wT_hi/lo[N][K] (32x32 tiles) -----------
__global__ __launch_bounds__(256) void k_wsplit(const float* __restrict__ w,
                                                unsigned short* __restrict__ th,
                                                unsigned short* __restrict__ tl,
                                                int K, int N) {
    __shared__ float t[32][33];
    int n0 = blockIdx.x * 32, k0 = blockIdx.y * 32;
    int c = threadIdx.x & 31, r0 = threadIdx.x >> 5;
#pragma unroll
    for (int it = 0; it < 4; ++it) {
        int r = r0 + it * 8;
        t[r][c] = w[(size_t)(k0 + r) * N + n0 + c];
    }
    __syncthreads();
#pragma unroll
    for (int it = 0; it < 4; ++it) {
        int r = r0 + it * 8;
        float v = t[c][r];
        unsigned short h = f2bf(v);
        th[(size_t)(n0 + r) * K + k0 + c] = h;
        tl[(size_t)(n0 + r) * K + k0 + c] = f2bf(v - bf2f(h));
    }
}

// ---------------- x_proj weight: w[1536][80] -> wX_hi/lo[80][1536] ----------------
__global__ __launch_bounds__(256) void k_wsplitX(const float* __restrict__ w,
                                                 unsigned short* __restrict__ th,
                                                 unsigned short* __restrict__ tl) {
    __shared__ float t[16][PJ];
    int k0 = blockIdx.x * 16;
    for (int i = threadIdx.x; i < 16 * PJ; i += 256)
        t[i / PJ][i % PJ] = w[(size_t)(k0 + i / PJ) * PJ + i % PJ];
    __syncthreads();
    for (int i = threadIdx.x; i < 16 * PJ; i += 256) {
        int j = i >> 4, kk = i & 15;     // j<80, kk<16
        float v = t[kk][j];
        unsigned short h = f2bf(v);
        th[(size_t)j * E_ + k0 + kk] = h;
        tl[(size_t)j * E_ + k0 + kk] = f2bf(v - bf2f(h));
    }
}

// ---------------- MFMA GEMM (bf16x2 split): C (+)= A[M,K] @ BT[N,K]^T ----------------
// 256 threads = 4 waves arranged WR x WC; wave tile (BM/WR) x (BN/WC); K-step 32.
// KS>1: grid.z splits K; block kz writes partial C at C + kz*M*N (ACCUM must be false).
template <int BM, int BN, int WR, int WC, bool ACCUM, int KS>
__global__ __launch_bounds__(256) void k_mmf(const unsigned short* __restrict__ Ah,
                                             const unsigned short* __restrict__ Al,
                                             const unsigned short* __restrict__ Bh,
                                             const unsigned short* __restrict__ Bl,
                                             float* __restrict__ C,
                                             int M, int N, int K) {
    constexpr int WM = BM / WR, WN = BN / WC;
    constexpr int MR = WM / 16, NR = WN / 16;
    constexpr int CA = 4 * BM, CB = 4 * BN;
    constexpr int RA = (CA + 255) / 256, RB = (CB + 255) / 256;
    __shared__ __align__(16) unsigned short sAh[CA * 8], sAl[CA * 8];
    __shared__ __align__(16) unsigned short sBh[CB * 8], sBl[CB * 8];
    int tid = threadIdx.x;
    int lane = tid & 63;
    int w = tid >> 6;
    int wr = w / WC, wc = w % WC;
    int m0 = blockIdx.y * BM, n0 = blockIdx.x * BN;
    int kz = (KS > 1) ? blockIdx.z : 0;
    int kb = kz * (K / KS), ke = kb + K / KS;

    f32x4 acc[MR][NR] = {};

    for (int k0 = kb; k0 < ke; k0 += 32) {
#pragma unroll
        for (int r = 0; r < RA; ++r) {
            int cell = (r * 4 + w) * 64 + lane;
            if (CA % 256 == 0 || cell < CA) {
                int oct = cell / BM, row = cell % BM;
                size_t go = (size_t)(m0 + row) * K + k0 + oct * 8;
                gl_lds16(Ah + go, &sAh[(size_t)cell * 8]);
                gl_lds16(Al + go, &sAl[(size_t)cell * 8]);
            }
        }
#pragma unroll
        for (int r = 0; r < RB; ++r) {
            int cell = (r * 4 + w) * 64 + lane;
            if (CB % 256 == 0 || cell < CB) {
                int oct = cell / BN, row = cell % BN;
                size_t go = (size_t)(n0 + row) * K + k0 + oct * 8;
                gl_lds16(Bh + go, &sBh[(size_t)cell * 8]);
                gl_lds16(Bl + go, &sBl[(size_t)cell * 8]);
            }
        }
        asm volatile("s_waitcnt vmcnt(0)" ::: "memory");
        __syncthreads();

        int oct = lane >> 4;
        int rl = lane & 15;
        bf16x8 ah[MR], al[MR], bh[NR], bl[NR];
#pragma unroll
        for (int i = 0; i < MR; ++i) {
            int row = wr * WM + i * 16 + rl;
            ah[i] = *(const bf16x8*)&sAh[(oct * BM + row) * 8];
            al[i] = *(const bf16x8*)&sAl[(oct * BM + row) * 8];
        }
#pragma unroll
        for (int j = 0; j < NR; ++j) {
            int row = wc * WN + j * 16 + rl;
            bh[j] = *(const bf16x8*)&sBh[(oct * BN + row) * 8];
            bl[j] = *(const bf16x8*)&sBl[(oct * BN + row) * 8];
        }
#pragma unroll
        for (int i = 0; i < MR; ++i)
#pragma unroll
            for (int j = 0; j < NR; ++j) {
                acc[i][j] = __builtin_amdgcn_mfma_f32_16x16x32_bf16(ah[i], bh[j], acc[i][j], 0, 0, 0);
                acc[i][j] = __builtin_amdgcn_mfma_f32_16x16x32_bf16(ah[i], bl[j], acc[i][j], 0, 0, 0);
                acc[i][j] = __builtin_amdgcn_mfma_f32_16x16x32_bf16(al[i], bh[j], acc[i][j], 0, 0, 0);
            }
        __syncthreads();
    }
    float* Cw = C + (size_t)kz * M * N;
    int rl = lane & 15, rq = lane >> 4;
#pragma unroll
    for (int i = 0; i < MR; ++i)
#pragma unroll
        for (int j = 0; j < NR; ++j)
#pragma unroll
            for (int v = 0; v < 4; ++v) {
                int row = m0 + wr * WM + i * 16 + rq * 4 + v;
                int col = n0 + wc * WN + j * 16 + rl;
                float val = acc[i][j][v];
                if (ACCUM) val += Cw[(size_t)row * N + col];
                Cw[(size_t)row * N + col] = val;
            }
}

// ---------------- K-split partial reduce: proj = sum_{kz} pp[kz] (x_proj) ----------------
__global__ __launch_bounds__(256) void k_padd(const float* __restrict__ pp,
                                              float* __restrict__ proj) {
    int idx = blockIdx.x * 256 + threadIdx.x;
    const int MN = BT_ * PJ;
    if (idx < MN)
        proj[idx] = pp[idx] + pp[MN + idx] + pp[2 * MN + idx] + pp[3 * MN + idx];
}

// ---------------- xz = ppA[0] + ppA[1]  (in_proj KS=2 reduce, float4) ----------------
__global__ __launch_bounds__(256) void k_sum2(const float* __restrict__ p,
                                              float* __restrict__ o) {
    size_t i = ((size_t)blockIdx.x * 256 + threadIdx.x) * 4;
    const size_t MN = (size_t)BT_ * 2 * E_;
    float4 a = *(const float4*)(p + i);
    float4 b = *(const float4*)(p + MN + i);
    *(float4*)(o + i) = make_float4(a.x + b.x, a.y + b.y, a.z + b.z, a.w + b.w);
}

// ---------------- h += ppB[0]+ppB[1]+ppB[2]  (out_proj KS=3 reduce, float4) ----------------
__global__ __launch_bounds__(256) void k_sum3(const float* __restrict__ p,
                                              float* __restrict__ o) {
    size_t i = ((size_t)blockIdx.x * 256 + threadIdx.x) * 4;
    const size_t MN = (size_t)BT_ * DM;
    float4 a = *(const float4*)(p + i);
    float4 b = *(const float4*)(p + MN + i);
    float4 c = *(const float4*)(p + 2 * MN + i);
    float4 h0 = *(const float4*)(o + i);
    *(float4*)(o + i) = make_float4(h0.x + a.x + b.x + c.x, h0.y + a.y + b.y + c.y,
                                    h0.z + a.z + b.z + c.z, h0.w + a.w + b.w + c.w);
}

// ---------------- causal depthwise conv (K=4) + SiLU; emits bf16 hi/lo only ---------------
__global__ __launch_bounds__(256) void k_conv(const float* __restrict__ xz,
                                              const float* __restrict__ cw,
                                              const float* __restrict__ cb,
                                              unsigned short* __restrict__ xch,
                                              unsigned short* __restrict__ xcl) {
    int idx = blockIdx.x * 256 + threadIdx.x;
    int e = idx % E_;
    int bt = idx / E_;
    int t = bt & (L_ - 1);
    const float* base = xz + (size_t)bt * (2 * E_) + e;
    float w0 = cw[e * 4 + 0], w1 = cw[e * 4 + 1], w2 = cw[e * 4 + 2], w3 = cw[e * 4 + 3];
    float acc = cb[e] + base[0] * w3;
    if (t >= 1) acc += base[-(2 * E_)] * w2;
    if (t >= 2) acc += base[-(4 * E_)] * w1;
    if (t >= 3) acc += base[-(6 * E_)] * w0;
    float v = siluf_(acc);
    unsigned short hh = f2bf(v);
    xch[idx] = hh;
    xcl[idx] = f2bf(v - bf2f(hh));
}

// ---------------- k_prep: dt GEMM(K=48)+softplus + transposed scan inputs ----------------
// x reconstructed exactly-enough from bf16 hi+lo (err ~2^-32 relative).
__global__ __launch_bounds__(256) void k_prep(const float* __restrict__ proj,
                                              const float* __restrict__ dw,
                                              const float* __restrict__ db,
                                              const unsigned short* __restrict__ xch,
                                              const unsigned short* __restrict__ xcl,
                                              const float* __restrict__ xz,
                                              const float* __restrict__ dp,
                                              float* __restrict__ dtT,
                                              float* __restrict__ dxT,
                                              float* __restrict__ xdT,
                                              float* __restrict__ zsT) {
    __shared__ float projS[64][48];
    __shared__ float dwS[48][64];
    __shared__ float tileT[64][65];
    int b = blockIdx.z;
    int t0 = blockIdx.x * 64;
    int e0 = blockIdx.y * 64;
    int tid = threadIdx.x;

    for (int idx = tid; idx < 64 * 48; idx += 256) {
        int tl = idx / 48, k = idx % 48;
        projS[tl][k] = proj[(size_t)(b * L_ + t0 + tl) * PJ + k];
    }
    for (int idx = tid; idx < 48 * 64; idx += 256) {
        int k = idx >> 6, ee = idx & 63;
        dwS[k][ee] = dw[(size_t)k * E_ + e0 + ee];
    }
    __syncthreads();

    int el = tid & 63;
    int tg = tid >> 6;
    float acc[16];
    float bvE = db[e0 + el];
#pragma unroll
    for (int s = 0; s < 16; ++s) acc[s] = bvE;
    for (int k = 0; k < 48; ++k) {
        float wv = dwS[k][el];
#pragma unroll
        for (int s = 0; s < 16; ++s) acc[s] += projS[tg * 16 + s][k] * wv;
    }
    float dtv[16];
#pragma unroll
    for (int s = 0; s < 16; ++s) dtv[s] = softplusf_(acc[s]);
    float xv[16];
#pragma unroll
    for (int s = 0; s < 16; ++s) {
        size_t ii = (size_t)(b * L_ + t0 + tg * 16 + s) * E_ + e0 + el;
        xv[s] = bf2f(xch[ii]) + bf2f(xcl[ii]);
    }
    float dpv = dp[e0 + el];

#define XPOSE_OUT(dst, EXPR)                                                      \
    do {                                                                          \
        __syncthreads();                                                          \
        for (int s = 0; s < 16; ++s) tileT[el][tg * 16 + s] = (EXPR);             \
        __syncthreads();                                                          \
        for (int idx = tid; idx < 4096; idx += 256) {                             \
            int e2 = idx >> 6, t2 = idx & 63;                                     \
            dst[((size_t)b * E_ + e0 + e2) * L_ + t0 + t2] = tileT[e2][t2];       \
        }                                                                         \
    } while (0)

    XPOSE_OUT(dtT, dtv[s]);
    XPOSE_OUT(dxT, dtv[s] * xv[s]);
    XPOSE_OUT(xdT, xv[s] * dpv);
    float zv[16];
#pragma unroll
    for (int s = 0; s < 16; ++s)
        zv[s] = xz[(size_t)(b * L_ + t0 + tg * 16 + s) * (2 * E_) + E_ + e0 + el];
    XPOSE_OUT(zsT, siluf_(zv[s]));
#undef XPOSE_OUT
}

// ---------------- chunked parallel selective scan v3 -> yzT f32 [b][e][t] ----------------
__global__ __launch_bounds__(256) void k_scan3(const float* __restrict__ dtT,
                                               const float* dxT,
                                               const float* __restrict__ xdT,
                                               const float* __restrict__ zsT,
                                               const float* __restrict__ proj,
                                               const float* __restrict__ A_log,
                                               float* yzT) {
    __shared__ float s_p[16 * 16 * 20];            // [c][s'][20] pad-20
    __shared__ float sAP[16][17], sAS[16][17], sH[16][17];
    int tid = threadIdx.x;
    int b = blockIdx.x / E_;
    int e = blockIdx.x - b * E_;
    size_t base = ((size_t)b * E_ + e) * L_;

    int c = tid >> 4;
    int n = tid & 15;
    float A = -expf(A_log[e * N_ + n]);

    int t0 = c * 32;
    const float* pdt = dtT + base + t0;
    const float* pdx = dxT + base + t0;
    const float* pb = proj + (size_t)(b * L_ + t0) * PJ + R_ + n;
    const float* pc = pb + N_;

    float dAr[32], ur[32];
    float P = 1.0f, S = 0.0f;
#pragma unroll
    for (int s = 0; s < 32; ++s) {
        float dA = expf(pdt[s] * A);
        float u = pdx[s] * pb[s * PJ];
        dAr[s] = dA;
        ur[s] = u;
        P *= dA;
        S = dA * S + u;
    }
    sAP[c][n] = P;
    sAS[c][n] = S;
    __syncthreads();
    if (tid < 16) {
        float Hc = 0.0f;
        for (int c2 = 0; c2 < 16; ++c2) {
            sH[c2][tid] = Hc;
            Hc = sAP[c2][tid] * Hc + sAS[c2][tid];
        }
    }
    __syncthreads();

    float h = sH[c][n];
    float* myrow = &s_p[(c * 16) * 20 + n];
    // ---- half 1: s = 0..15 ----
#pragma unroll
    for (int s = 0; s < 16; ++s) {
        h = dAr[s] * h + ur[s];
        myrow[s * 20] = h * pc[s * PJ];
    }
    __syncthreads();
    {
        int rc = tid >> 4, rs = tid & 15;
        const float* row = &s_p[(rc * 16 + rs) * 20];
        f32x4 v0 = *(const f32x4*)&row[0];
        f32x4 v1 = *(const f32x4*)&row[4];
        f32x4 v2 = *(const f32x4*)&row[8];
        f32x4 v3 = *(const f32x4*)&row[12];
        float sum = (v0[0]+v0[1]+v0[2]+v0[3]) + (v1[0]+v1[1]+v1[2]+v1[3]) +
                    (v2[0]+v2[1]+v2[2]+v2[3]) + (v3[0]+v3[1]+v3[2]+v3[3]);
        int t = rc * 32 + rs;
        yzT[base + t] = (sum + xdT[base + t]) * zsT[base + t];
    }
    __syncthreads();
    // ---- half 2: s = 16..31 ----
#pragma unroll
    for (int s = 0; s < 16; ++s) {
        h = dAr[16 + s] * h + ur[16 + s];
        myrow[s * 20] = h * pc[(16 + s) * PJ];
    }
    __syncthreads();
    {
        int rc = tid >> 4, rs = tid & 15;
        const float* row = &s_p[(rc * 16 + rs) * 20];
        f32x4 v0 = *(const f32x4*)&row[0];
        f32x4 v1 = *(const f32x4*)&row[4];
        f32x4 v2 = *(const f32x4*)&row[8];
        f32x4 v3 = *(const f32x4*)&row[12];
        float sum = (v0[0]+v0[1]+v0[2]+v0[3]) + (v1[0]+v1[1]+v1[2]+v1[3]) +
                    (v2[0]+v2[1]+v2[2]+v2[3]) + (v3[0]+v3[1]+v3[2]+v3[3]);
        int t = rc * 32 + 16 + rs;
        yzT[base + t] = (sum + xdT[base + t]) * zsT[base + t];
    }
}

// ---------------- yzT [b][e][t] f32 -> yz_h/yz_l [bt][e] bf16 (64x64 LDS transpose) --------
__global__ __launch_bounds__(256) void k_ytr(const float* __restrict__ yzT,
                                             unsigned short* __restrict__ yzh,
                                             unsigned short* __restrict__ yzl) {
    __shared__ float t[64][65];
    int b = blockIdx.z;
    int t0 = blockIdx.x * 64;
    int e0 = blockIdx.y * 64;
    int tid = threadIdx.x;
    for (int idx = tid; idx < 4096; idx += 256) {
        int e2 = idx >> 6, t2 = idx & 63;
        t[e2][t2] = yzT[((size_t)b * E_ + e0 + e2) * L_ + t0 + t2];
    }
    __syncthreads();
    for (int idx = tid; idx < 4096; idx += 256) {
        int t2 = idx >> 6, e2 = idx & 63;
        float v = t[e2][t2];
        unsigned short hh = f2bf(v);
        size_t o = (size_t)(b * L_ + t0 + t2) * E_ + e0 + e2;
        yzh[o] = hh;
        yzl[o] = f2bf(v - bf2f(hh));
    }
}

// ---------------- head: hrel = relu(cls @ top_w + top_b) ----------------
__global__ __launch_bounds__(256) void k_top(const float* __restrict__ cls,
                                             const float* __restrict__ w,
                                             const float* __restrict__ bias,
                                             float* __restrict__ hrel) {
    __shared__ float xs[B_][DM];
    __shared__ float red[4][64][B_];
    int tid = threadIdx.x;
    for (int c = tid; c < B_ * DM; c += 256) ((float*)xs)[c] = cls[c];
    __syncthreads();
    int jl = tid & 63;
    int kq = tid >> 6;
    int j = blockIdx.x * 64 + jl;
    float acc[B_] = {};
    for (int k = kq * (DM / 4); k < (kq + 1) * (DM / 4); ++k) {
        float wv = w[(size_t)k * H_ + j];
#pragma unroll
        for (int b = 0; b < B_; ++b) acc[b] += xs[b][k] * wv;
    }
#pragma unroll
    for (int b = 0; b < B_; ++b) red[kq][jl][b] = acc[b];
    __syncthreads();
    if (kq == 0) {
        float bv = bias[j];
#pragma unroll
        for (int b = 0; b < B_; ++b) {
            float s = red[0][jl][b] + red[1][jl][b] + red[2][jl][b] + red[3][jl][b] + bv;
            hrel[(size_t)b * H_ + j] = fmaxf(s, 0.0f);
        }
    }
}

// ---------------- head: out = hrel @ bot_w + bot_b ----------------
__global__ __launch_bounds__(256) void k_bot(const float* __restrict__ hrel,
                                             const float* __restrict__ w,
                                             const float* __restrict__ bias,
                                             float* __restrict__ out) {
    __shared__ float red[8][T_];
    int b = blockIdx.x;
    int jl = threadIdx.x & 31;
    int kq = threadIdx.x >> 5;
    if (jl < T_) {
        float acc = 0.0f;
        for (int k = kq * (H_ / 8); k < (kq + 1) * (H_ / 8); ++k)
            acc += hrel[(size_t)b * H_ + k] * w[(size_t)k * T_ + jl];
        red[kq][jl] = acc;
    }
    __syncthreads();
    if (kq == 0 && jl < T_) {
        float s = bias[jl];
#pragma unroll
        for (int q = 0; q < 8; ++q) s += red[q][jl];
        out[(size_t)b * T_ + jl] = s;
    }
}

extern "C" void kernel_launch(void* const* d_in, const int* in_sizes, int n_in,
                              void* d_out, int out_size, void* d_ws, size_t ws_size,
                              hipStream_t stream) {
    const int*   ids       = (const int*)d_in[0];
    const float* embed     = (const float*)d_in[1];
    const float* in_proj_w = (const float*)d_in[2];
    const float* conv_w    = (const float*)d_in[3];
    const float* conv_b    = (const float*)d_in[4];
    const float* x_proj_w  = (const float*)d_in[5];
    const float* dt_w      = (const float*)d_in[6];
    const float* dt_b      = (const float*)d_in[7];
    const float* A_log     = (const float*)d_in[8];
    const float* D_p       = (const float*)d_in[9];
    const float* out_w     = (const float*)d_in[10];
    const float* norm_w    = (const float*)d_in[11];
    const float* norm_f_w  = (const float*)d_in[12];
    const float* top_w     = (const float*)d_in[13];
    const float* top_b     = (const float*)d_in[14];
    const float* bot_w     = (const float*)d_in[15];
    const float* bot_b     = (const float*)d_in[16];
    float* out = (float*)d_out;

    // workspace layout
    float* ws = (float*)d_ws;
    float* h    = ws;                         // 2048*768
    float* xz   = h + (size_t)BT_ * DM;       // 2048*3072
    float* proj = xz + (size_t)BT_ * 2 * E_;  // 2048*80
    float* dtT  = proj + (size_t)BT_ * PJ;    // 2048*1536 ([b][e][t])
    float* dxT  = dtT + (size_t)BT_ * E_;     // also reused as yzT (aliased on purpose)
    float* xdT  = dxT + (size_t)BT_ * E_;
    float* zsT  = xdT + (size_t)BT_ * E_;
    float* cls  = zsT + (size_t)BT_ * E_;     // 4*768
    float* hrel = cls + (size_t)B_ * DM;      // 4*1536
    unsigned short* us = (unsigned short*)(hrel + (size_t)B_ * H_);
    unsigned short* xi_h = us;                              // 2048*768
    unsigned short* xi_l = xi_h + (size_t)BT_ * DM;
    unsigned short* yz_h = xi_l + (size_t)BT_ * DM;         // 2048*1536
    unsigned short* yz_l = yz_h + (size_t)BT_ * E_;
    unsigned short* wA_h = yz_l + (size_t)BT_ * E_;         // 3072*768
    unsigned short* wA_l = wA_h + (size_t)(2 * E_) * DM;
    unsigned short* wB_h = wA_l + (size_t)(2 * E_) * DM;    // 768*1536
    unsigned short* wB_l = wB_h + (size_t)DM * E_;
    unsigned short* xc_h = wB_l + (size_t)DM * E_;          // 2048*1536
    unsigned short* xc_l = xc_h + (size_t)BT_ * E_;
    unsigned short* wX_h = xc_l + (size_t)BT_ * E_;         // 80*1536
    unsigned short* wX_l = wX_h + (size_t)PJ * E_;
    float* pp  = (float*)(wX_l + (size_t)PJ * E_);          // 4*2048*80  (x_proj partials)
    float* ppA = pp + (size_t)4 * BT_ * PJ;                 // 2*2048*3072 (in_proj partials)
    float* ppB = ppA + (size_t)2 * BT_ * 2 * E_;            // 3*2048*768  (out_proj partials)
    float* yzT = dxT;   // alias: safe (see k_scan3 comment)

    k_embed<<<BT_, 256, 0, stream>>>(ids, embed, h);

    for (int i = 0; i < NL_; ++i) {
        const float* ipw = in_proj_w + (size_t)i * DM * 2 * E_;
        const float* cwi = conv_w + (size_t)i * E_ * K_;
        const float* cbi = conv_b + (size_t)i * E_;
        const float* xpw = x_proj_w + (size_t)i * E_ * PJ;
        const float* dwi = dt_w + (size_t)i * R_ * E_;
        const float* dbi = dt_b + (size_t)i * E_;
        const float* ali = A_log + (size_t)i * E_ * N_;
        const float* dpi = D_p + (size_t)i * E_;
        const float* owi = out_w + (size_t)i * E_ * DM;
        const float* nwi = norm_w + (size_t)i * DM;

        k_rmsnorm<true><<<BT_, 256, 0, stream>>>(h, DM, nwi, nullptr, xi_h, xi_l);
        k_wsplit<<<dim3(2 * E_ / 32, DM / 32), 256, 0, stream>>>(ipw, wA_h, wA_l, DM, 2 * E_);
        // xz = xi @ in_proj (MFMA bf16x2): 128x128 tile, KS=2 -> 768 blocks (~3/CU)
        k_mmf<128, 128, 2, 2, false, 2><<<dim3(2 * E_ / 128, BT_ / 128, 2), 256, 0, stream>>>(
            xi_h, xi_l, wA_h, wA_l, ppA, BT_, 2 * E_, DM);
        k_sum2<<<BT_ * 2 * E_ / 1024, 256, 0, stream>>>(ppA, xz);
        k_conv<<<BT_ * E_ / 256, 256, 0, stream>>>(xz, cwi, cbi, xc_h, xc_l);
        // x_proj: proj[2048][80] = xc @ wX^T, K-split 4 + reduce
        k_wsplitX<<<E_ / 16, 256, 0, stream>>>(xpw, wX_h, wX_l);
        k_mmf<128, PJ, 4, 1, false, 4><<<dim3(1, BT_ / 128, 4), 256, 0, stream>>>(
            xc_h, xc_l, wX_h, wX_l, pp, BT_, PJ, E_);
        k_padd<<<(BT_ * PJ + 255) / 256, 256, 0, stream>>>(pp, proj);
        k_prep<<<dim3(L_ / 64, E_ / 64, B_), 256, 0, stream>>>(
            proj, dwi, dbi, xc_h, xc_l, xz, dpi, dtT, dxT, xdT, zsT);
        k_scan3<<<B_ * E_, 256, 0, stream>>>(dtT, dxT, xdT, zsT, proj, ali, yzT);
        k_ytr<<<dim3(L_ / 64, E_ / 64, B_), 256, 0, stream>>>(yzT, yz_h, yz_l);
        k_wsplit<<<dim3(DM / 32, E_ / 32), 256, 0, stream>>>(owi, wB_h, wB_l, E_, DM);
        // out_proj: 64x64 tile, KS=3 -> 1152 blocks (~4.5/CU); then h += partials
        k_mmf<64, 64, 2, 2, false, 3><<<dim3(DM / 64, BT_ / 64, 3), 256, 0, stream>>>(
            yz_h, yz_l, wB_h, wB_l, ppB, BT_, DM, E_);
        k_sum3<<<BT_ * DM / 1024, 256, 0, stream>>>(ppB, h);
    }

    k_rmsnorm<false><<<B_, 256, 0, stream>>>(h + (size_t)(L_ - 1) * DM, (long)L_ * DM,
                                             norm_f_w, cls, nullptr, nullptr);
    k_top<<<H_ / 64, 256, 0, stream>>>(cls, top_w, top_b, hrel);
    k_bot<<<B_, 256, 0, stream>>>(hrel, bot_w, bot_b, out);
}

// Round 13
// 1208.295 us; speedup vs baseline: 1.0631x; 1.0631x over previous
//
#include <hip/hip_runtime.h>
#include <hip/hip_bf16.h>
#include <math.h>

// Problem constants
#define B_ 4
#define L_ 512
#define DM 768
#define E_ 1536
#define N_ 16
#define R_ 48
#define K_ 4
#define NL_ 4
#define H_ 1536
#define T_ 28
#define BT_ (B_ * L_)   // 2048 tokens
#define PJ 80           // R_ + 2*N_

typedef __bf16 bf16x8 __attribute__((ext_vector_type(8)));
typedef float  f32x4  __attribute__((ext_vector_type(4)));

// fast transcendentals: __expf/__logf are single v_exp/v_log sequences (rel err ~2^-21),
// plenty for our ~5e-4 absmax budget.
__device__ __forceinline__ float sigmoidf_(float v) { return 1.0f / (1.0f + __expf(-v)); }
__device__ __forceinline__ float siluf_(float v) { return v * sigmoidf_(v); }
__device__ __forceinline__ float softplusf_(float v) {
    // log1p(y) ~ __logf(1+y): for y<1e-7 both ~y (abs err <1e-7)
    return fmaxf(v, 0.0f) + __logf(1.0f + __expf(-fabsf(v)));
}
__device__ __forceinline__ unsigned short f2bf(float x) {
    unsigned u = __float_as_uint(x);
    u = u + 0x7fffu + ((u >> 16) & 1u);
    return (unsigned short)(u >> 16);
}
__device__ __forceinline__ float bf2f(unsigned short h) {
    return __uint_as_float(((unsigned)h) << 16);
}
__device__ __forceinline__ void gl_lds16(const void* g, void* l) {
    auto gp = reinterpret_cast<const __attribute__((address_space(1))) unsigned int*>(
        reinterpret_cast<uintptr_t>(g));
    auto lp = reinterpret_cast<__attribute__((address_space(3))) unsigned int*>(
        reinterpret_cast<uintptr_t>(l));
    __builtin_amdgcn_global_load_lds(gp, lp, 16, 0, 0);
}

// ---------------- embed gather ----------------
__global__ __launch_bounds__(256) void k_embed(const int* __restrict__ ids,
                                               const float* __restrict__ embed,
                                               float* __restrict__ h) {
    int bt = blockIdx.x;
    int tok = ids[bt];
    const float* src = embed + (size_t)tok * DM;
    float* dst = h + (size_t)bt * DM;
    for (int c = threadIdx.x; c < DM; c += 256) dst[c] = src[c];
}

// ---------------- RMSNorm; BF=true emits bf16 hi/lo split ----------------
template <bool BF>
__global__ __launch_bounds__(256) void k_rmsnorm(const float* __restrict__ base, long rstride,
                                                 const float* __restrict__ w,
                                                 float* __restrict__ outf,
                                                 unsigned short* __restrict__ oh,
                                                 unsigned short* __restrict__ ol) {
    int tid = threadIdx.x;
    const float* row = base + (size_t)blockIdx.x * rstride;
    float v0 = row[tid], v1 = row[tid + 256], v2 = row[tid + 512];
    float s = v0 * v0 + v1 * v1 + v2 * v2;
#pragma unroll
    for (int m = 1; m < 64; m <<= 1) s += __shfl_xor(s, m);
    __shared__ float red[4];
    if ((tid & 63) == 0) red[tid >> 6] = s;
    __syncthreads();
    s = red[0] + red[1] + red[2] + red[3];
    float rs = rsqrtf(s * (1.0f / (float)DM) + 1e-5f);
    float r0 = v0 * rs * w[tid];
    float r1 = v1 * rs * w[tid + 256];
    float r2 = v2 * rs * w[tid + 512];
    size_t o = (size_t)blockIdx.x * DM;
    if (BF) {
        unsigned short h0 = f2bf(r0), h1 = f2bf(r1), h2 = f2bf(r2);
        oh[o + tid] = h0;        ol[o + tid] = f2bf(r0 - bf2f(h0));
        oh[o + tid + 256] = h1;  ol[o + tid + 256] = f2bf(r1 - bf2f(h1));
        oh[o + tid + 512] = h2;  ol[o + tid + 512] = f2bf(r2 - bf2f(h2));
    } else {
        outf[o + tid] = r0;
        outf[o + tid + 256] = r1;
        outf[o + tid + 512] = r2;
    }
}

// ---------------- weight transpose + split, all layers: w[z][K][N] -> wT[z][N][K] -----------
__global__ __launch_bounds__(256) void k_wsplit(const float* __restrict__ w,
                                                unsigned short* __restrict__ th,
                                                unsigned short* __restrict__ tl,
                                                int K, int N) {
    __shared__ float t[32][33];
    size_t off = (size_t)blockIdx.z * K * N;
    const float* wz = w + off;
    unsigned short* thz = th + off;
    unsigned short* tlz = tl + off;
    int n0 = blockIdx.x * 32, k0 = blockIdx.y * 32;
    int c = threadIdx.x & 31, r0 = threadIdx.x >> 5;
#pragma unroll
    for (int it = 0; it < 4; ++it) {
        int r = r0 + it * 8;
        t[r][c] = wz[(size_t)(k0 + r) * N + n0 + c];
    }
    __syncthreads();
#pragma unroll
    for (int it = 0; it < 4; ++it) {
        int r = r0 + it * 8;
        float v = t[c][r];
        unsigned short h = f2bf(v);
        thz[(size_t)(n0 + r) * K + k0 + c] = h;
        tlz[(size_t)(n0 + r) * K + k0 + c] = f2bf(v - bf2f(h));
    }
}

// ---------------- x_proj weight, all layers: w[z][1536][80] -> wX[z][80][1536] ----------------
__global__ __launch_bounds__(256) void k_wsplitX(const float* __restrict__ w,
                                                 unsigned short* __restrict__ th,
                                                 unsigned short* __restrict__ tl) {
    __shared__ float t[16][PJ];
    size_t off = (size_t)blockIdx.z * E_ * PJ;
    const float* wz = w + off;
    unsigned short* thz = th + off;
    unsigned short* tlz = tl + off;
    int k0 = blockIdx.x * 16;
    for (int i = threadIdx.x; i < 16 * PJ; i += 256)
        t[i / PJ][i % PJ] = wz[(size_t)(k0 + i / PJ) * PJ + i % PJ];
    __syncthreads();
    for (int i = threadIdx.x; i < 16 * PJ; i += 256) {
        int j = i >> 4, kk = i & 15;     // j<80, kk<16
        float v = t[kk][j];
        unsigned short h = f2bf(v);
        thz[(size_t)j * E_ + k0 + kk] = h;
        tlz[(size_t)j * E_ + k0 + kk] = f2bf(v - bf2f(h));
    }
}

// ---------------- MFMA GEMM (bf16x2 split): C (+)= A[M,K] @ BT[N,K]^T ----------------
// 256 threads = 4 waves arranged WR x WC; wave tile (BM/WR) x (BN/WC); K-step 32.
// KS>1: grid.z splits K; block kz writes partial C at C + kz*M*N (ACCUM must be false).
template <int BM, int BN, int WR, int WC, bool ACCUM, int KS>
__global__ __launch_bounds__(256) void k_mmf(const unsigned short* __restrict__ Ah,
                                             const unsigned short* __restrict__ Al,
                                             const unsigned short* __restrict__ Bh,
                                             const unsigned short* __restrict__ Bl,
                                             float* __restrict__ C,
                                             int M, int N, int K) {
    constexpr int WM = BM / WR, WN = BN / WC;
    constexpr int MR = WM / 16, NR = WN / 16;
    constexpr int CA = 4 * BM, CB = 4 * BN;
    constexpr int RA = (CA + 255) / 256, RB = (CB + 255) / 256;
    __shared__ __align__(16) unsigned short sAh[CA * 8], sAl[CA * 8];
    __shared__ __align__(16) unsigned short sBh[CB * 8], sBl[CB * 8];
    int tid = threadIdx.x;
    int lane = tid & 63;
    int w = tid >> 6;
    int wr = w / WC, wc = w % WC;
    int m0 = blockIdx.y * BM, n0 = blockIdx.x * BN;
    int kz = (KS > 1) ? blockIdx.z : 0;
    int kb = kz * (K / KS), ke = kb + K / KS;

    f32x4 acc[MR][NR] = {};

    for (int k0 = kb; k0 < ke; k0 += 32) {
#pragma unroll
        for (int r = 0; r < RA; ++r) {
            int cell = (r * 4 + w) * 64 + lane;
            if (CA % 256 == 0 || cell < CA) {
                int oct = cell / BM, row = cell % BM;
                size_t go = (size_t)(m0 + row) * K + k0 + oct * 8;
                gl_lds16(Ah + go, &sAh[(size_t)cell * 8]);
                gl_lds16(Al + go, &sAl[(size_t)cell * 8]);
            }
        }
#pragma unroll
        for (int r = 0; r < RB; ++r) {
            int cell = (r * 4 + w) * 64 + lane;
            if (CB % 256 == 0 || cell < CB) {
                int oct = cell / BN, row = cell % BN;
                size_t go = (size_t)(n0 + row) * K + k0 + oct * 8;
                gl_lds16(Bh + go, &sBh[(size_t)cell * 8]);
                gl_lds16(Bl + go, &sBl[(size_t)cell * 8]);
            }
        }
        asm volatile("s_waitcnt vmcnt(0)" ::: "memory");
        __syncthreads();

        int oct = lane >> 4;
        int rl = lane & 15;
        bf16x8 ah[MR], al[MR], bh[NR], bl[NR];
#pragma unroll
        for (int i = 0; i < MR; ++i) {
            int row = wr * WM + i * 16 + rl;
            ah[i] = *(const bf16x8*)&sAh[(oct * BM + row) * 8];
            al[i] = *(const bf16x8*)&sAl[(oct * BM + row) * 8];
        }
#pragma unroll
        for (int j = 0; j < NR; ++j) {
            int row = wc * WN + j * 16 + rl;
            bh[j] = *(const bf16x8*)&sBh[(oct * BN + row) * 8];
            bl[j] = *(const bf16x8*)&sBl[(oct * BN + row) * 8];
        }
#pragma unroll
        for (int i = 0; i < MR; ++i)
#pragma unroll
            for (int j = 0; j < NR; ++j) {
                acc[i][j] = __builtin_amdgcn_mfma_f32_16x16x32_bf16(ah[i], bh[j], acc[i][j], 0, 0, 0);
                acc[i][j] = __builtin_amdgcn_mfma_f32_16x16x32_bf16(ah[i], bl[j], acc[i][j], 0, 0, 0);
                acc[i][j] = __builtin_amdgcn_mfma_f32_16x16x32_bf16(al[i], bh[j], acc[i][j], 0, 0, 0);
            }
        __syncthreads();
    }
    float* Cw = C + (size_t)kz * M * N;
    int rl = lane & 15, rq = lane >> 4;
#pragma unroll
    for (int i = 0; i < MR; ++i)
#pragma unroll
        for (int j = 0; j < NR; ++j)
#pragma unroll
            for (int v = 0; v < 4; ++v) {
                int row = m0 + wr * WM + i * 16 + rq * 4 + v;
                int col = n0 + wc * WN + j * 16 + rl;
                float val = acc[i][j][v];
                if (ACCUM) val += Cw[(size_t)row * N + col];
                Cw[(size_t)row * N + col] = val;
            }
}

// ---------------- K-split partial reduce: proj = sum_{kz} pp[kz] (x_proj) ----------------
__global__ __launch_bounds__(256) void k_padd(const float* __restrict__ pp,
                                              float* __restrict__ proj) {
    int idx = blockIdx.x * 256 + threadIdx.x;
    const int MN = BT_ * PJ;
    if (idx < MN)
        proj[idx] = pp[idx] + pp[MN + idx] + pp[2 * MN + idx] + pp[3 * MN + idx];
}

// ---------------- causal depthwise conv (K=4) + SiLU; emits bf16 hi/lo only ---------------
__global__ __launch_bounds__(256) void k_conv(const float* __restrict__ xz,
                                              const float* __restrict__ cw,
                                              const float* __restrict__ cb,
                                              unsigned short* __restrict__ xch,
                                              unsigned short* __restrict__ xcl) {
    int idx = blockIdx.x * 256 + threadIdx.x;
    int e = idx % E_;
    int bt = idx / E_;
    int t = bt & (L_ - 1);
    const float* base = xz + (size_t)bt * (2 * E_) + e;
    float w0 = cw[e * 4 + 0], w1 = cw[e * 4 + 1], w2 = cw[e * 4 + 2], w3 = cw[e * 4 + 3];
    float acc = cb[e] + base[0] * w3;
    if (t >= 1) acc += base[-(2 * E_)] * w2;
    if (t >= 2) acc += base[-(4 * E_)] * w1;
    if (t >= 3) acc += base[-(6 * E_)] * w0;
    float v = siluf_(acc);
    unsigned short hh = f2bf(v);
    xch[idx] = hh;
    xcl[idx] = f2bf(v - bf2f(hh));
}

// ---------------- k_prep: dt GEMM(K=48)+softplus + transposed scan inputs ----------------
__global__ __launch_bounds__(256) void k_prep(const float* __restrict__ proj,
                                              const float* __restrict__ dw,
                                              const float* __restrict__ db,
                                              const unsigned short* __restrict__ xch,
                                              const unsigned short* __restrict__ xcl,
                                              const float* __restrict__ xz,
                                              const float* __restrict__ dp,
                                              float* __restrict__ dtT,
                                              float* __restrict__ dxT,
                                              float* __restrict__ xdT,
                                              float* __restrict__ zsT) {
    __shared__ float projS[64][48];
    __shared__ float dwS[48][64];
    __shared__ float tileT[64][65];
    int b = blockIdx.z;
    int t0 = blockIdx.x * 64;
    int e0 = blockIdx.y * 64;
    int tid = threadIdx.x;

    for (int idx = tid; idx < 64 * 48; idx += 256) {
        int tl = idx / 48, k = idx % 48;
        projS[tl][k] = proj[(size_t)(b * L_ + t0 + tl) * PJ + k];
    }
    for (int idx = tid; idx < 48 * 64; idx += 256) {
        int k = idx >> 6, ee = idx & 63;
        dwS[k][ee] = dw[(size_t)k * E_ + e0 + ee];
    }
    __syncthreads();

    int el = tid & 63;
    int tg = tid >> 6;
    float acc[16];
    float bvE = db[e0 + el];
#pragma unroll
    for (int s = 0; s < 16; ++s) acc[s] = bvE;
    for (int k = 0; k < 48; ++k) {
        float wv = dwS[k][el];
#pragma unroll
        for (int s = 0; s < 16; ++s) acc[s] += projS[tg * 16 + s][k] * wv;
    }
    float dtv[16];
#pragma unroll
    for (int s = 0; s < 16; ++s) dtv[s] = softplusf_(acc[s]);
    float xv[16];
#pragma unroll
    for (int s = 0; s < 16; ++s) {
        size_t ii = (size_t)(b * L_ + t0 + tg * 16 + s) * E_ + e0 + el;
        xv[s] = bf2f(xch[ii]) + bf2f(xcl[ii]);
    }
    float dpv = dp[e0 + el];

#define XPOSE_OUT(dst, EXPR)                                                      \
    do {                                                                          \
        __syncthreads();                                                          \
        for (int s = 0; s < 16; ++s) tileT[el][tg * 16 + s] = (EXPR);             \
        __syncthreads();                                                          \
        for (int idx = tid; idx < 4096; idx += 256) {                             \
            int e2 = idx >> 6, t2 = idx & 63;                                     \
            dst[((size_t)b * E_ + e0 + e2) * L_ + t0 + t2] = tileT[e2][t2];       \
        }                                                                         \
    } while (0)

    XPOSE_OUT(dtT, dtv[s]);
    XPOSE_OUT(dxT, dtv[s] * xv[s]);
    XPOSE_OUT(xdT, xv[s] * dpv);
    float zv[16];
#pragma unroll
    for (int s = 0; s < 16; ++s)
        zv[s] = xz[(size_t)(b * L_ + t0 + tg * 16 + s) * (2 * E_) + E_ + e0 + el];
    XPOSE_OUT(zsT, siluf_(zv[s]));
#undef XPOSE_OUT
}

// ---------------- chunked parallel selective scan v3 -> yzT f32 [b][e][t] ----------------
__global__ __launch_bounds__(256) void k_scan3(const float* __restrict__ dtT,
                                               const float* dxT,
                                               const float* __restrict__ xdT,
                                               const float* __restrict__ zsT,
                                               const float* __restrict__ proj,
                                               const float* __restrict__ A_log,
                                               float* yzT) {
    __shared__ float s_p[16 * 16 * 20];            // [c][s'][20] pad-20
    __shared__ float sAP[16][17], sAS[16][17], sH[16][17];
    int tid = threadIdx.x;
    int b = blockIdx.x / E_;
    int e = blockIdx.x - b * E_;
    size_t base = ((size_t)b * E_ + e) * L_;

    int c = tid >> 4;
    int n = tid & 15;
    float A = -__expf(A_log[e * N_ + n]);

    int t0 = c * 32;
    const float* pdt = dtT + base + t0;
    const float* pdx = dxT + base + t0;
    const float* pb = proj + (size_t)(b * L_ + t0) * PJ + R_ + n;
    const float* pc = pb + N_;

    float dAr[32], ur[32];
    float P = 1.0f, S = 0.0f;
#pragma unroll
    for (int s = 0; s < 32; ++s) {
        float dA = __expf(pdt[s] * A);
        float u = pdx[s] * pb[s * PJ];
        dAr[s] = dA;
        ur[s] = u;
        P *= dA;
        S = dA * S + u;
    }
    sAP[c][n] = P;
    sAS[c][n] = S;
    __syncthreads();
    if (tid < 16) {
        float Hc = 0.0f;
        for (int c2 = 0; c2 < 16; ++c2) {
            sH[c2][tid] = Hc;
            Hc = sAP[c2][tid] * Hc + sAS[c2][tid];
        }
    }
    __syncthreads();

    float h = sH[c][n];
    float* myrow = &s_p[(c * 16) * 20 + n];
    // ---- half 1: s = 0..15 ----
#pragma unroll
    for (int s = 0; s < 16; ++s) {
        h = dAr[s] * h + ur[s];
        myrow[s * 20] = h * pc[s * PJ];
    }
    __syncthreads();
    {
        int rc = tid >> 4, rs = tid & 15;
        const float* row = &s_p[(rc * 16 + rs) * 20];
        f32x4 v0 = *(const f32x4*)&row[0];
        f32x4 v1 = *(const f32x4*)&row[4];
        f32x4 v2 = *(const f32x4*)&row[8];
        f32x4 v3 = *(const f32x4*)&row[12];
        float sum = (v0[0]+v0[1]+v0[2]+v0[3]) + (v1[0]+v1[1]+v1[2]+v1[3]) +
                    (v2[0]+v2[1]+v2[2]+v2[3]) + (v3[0]+v3[1]+v3[2]+v3[3]);
        int t = rc * 32 + rs;
        yzT[base + t] = (sum + xdT[base + t]) * zsT[base + t];
    }
    __syncthreads();
    // ---- half 2: s = 16..31 ----
#pragma unroll
    for (int s = 0; s < 16; ++s) {
        h = dAr[16 + s] * h + ur[16 + s];
        myrow[s * 20] = h * pc[(16 + s) * PJ];
    }
    __syncthreads();
    {
        int rc = tid >> 4, rs = tid & 15;
        const float* row = &s_p[(rc * 16 + rs) * 20];
        f32x4 v0 = *(const f32x4*)&row[0];
        f32x4 v1 = *(const f32x4*)&row[4];
        f32x4 v2 = *(const f32x4*)&row[8];
        f32x4 v3 = *(const f32x4*)&row[12];
        float sum = (v0[0]+v0[1]+v0[2]+v0[3]) + (v1[0]+v1[1]+v1[2]+v1[3]) +
                    (v2[0]+v2[1]+v2[2]+v2[3]) + (v3[0]+v3[1]+v3[2]+v3[3]);
        int t = rc * 32 + 16 + rs;
        yzT[base + t] = (sum + xdT[base + t]) * zsT[base + t];
    }
}

// ---------------- yzT [b][e][t] f32 -> yz_h/yz_l [bt][e] bf16 (64x64 LDS transpose) --------
__global__ __launch_bounds__(256) void k_ytr(const float* __restrict__ yzT,
                                             unsigned short* __restrict__ yzh,
                                             unsigned short* __restrict__ yzl) {
    __shared__ float t[64][65];
    int b = blockIdx.z;
    int t0 = blockIdx.x * 64;
    int e0 = blockIdx.y * 64;
    int tid = threadIdx.x;
    for (int idx = tid; idx < 4096; idx += 256) {
        int e2 = idx >> 6, t2 = idx & 63;
        t[e2][t2] = yzT[((size_t)b * E_ + e0 + e2) * L_ + t0 + t2];
    }
    __syncthreads();
    for (int idx = tid; idx < 4096; idx += 256) {
        int t2 = idx >> 6, e2 = idx & 63;
        float v = t[e2][t2];
        unsigned short hh = f2bf(v);
        size_t o = (size_t)(b * L_ + t0 + t2) * E_ + e0 + e2;
        yzh[o] = hh;
        yzl[o] = f2bf(v - bf2f(hh));
    }
}

// ---------------- head: hrel = relu(cls @ top_w + top_b) ----------------
__global__ __launch_bounds__(256) void k_top(const float* __restrict__ cls,
                                             const float* __restrict__ w,
                                             const float* __restrict__ bias,
                                             float* __restrict__ hrel) {
    __shared__ float xs[B_][DM];
    __shared__ float red[4][64][B_];
    int tid = threadIdx.x;
    for (int c = tid; c < B_ * DM; c += 256) ((float*)xs)[c] = cls[c];
    __syncthreads();
    int jl = tid & 63;
    int kq = tid >> 6;
    int j = blockIdx.x * 64 + jl;
    float acc[B_] = {};
    for (int k = kq * (DM / 4); k < (kq + 1) * (DM / 4); ++k) {
        float wv = w[(size_t)k * H_ + j];
#pragma unroll
        for (int b = 0; b < B_; ++b) acc[b] += xs[b][k] * wv;
    }
#pragma unroll
    for (int b = 0; b < B_; ++b) red[kq][jl][b] = acc[b];
    __syncthreads();
    if (kq == 0) {
        float bv = bias[j];
#pragma unroll
        for (int b = 0; b < B_; ++b) {
            float s = red[0][jl][b] + red[1][jl][b] + red[2][jl][b] + red[3][jl][b] + bv;
            hrel[(size_t)b * H_ + j] = fmaxf(s, 0.0f);
        }
    }
}

// ---------------- head: out = hrel @ bot_w + bot_b ----------------
__global__ __launch_bounds__(256) void k_bot(const float* __restrict__ hrel,
                                             const float* __restrict__ w,
                                             const float* __restrict__ bias,
                                             float* __restrict__ out) {
    __shared__ float red[8][T_];
    int b = blockIdx.x;
    int jl = threadIdx.x & 31;
    int kq = threadIdx.x >> 5;
    if (jl < T_) {
        float acc = 0.0f;
        for (int k = kq * (H_ / 8); k < (kq + 1) * (H_ / 8); ++k)
            acc += hrel[(size_t)b * H_ + k] * w[(size_t)k * T_ + jl];
        red[kq][jl] = acc;
    }
    __syncthreads();
    if (kq == 0 && jl < T_) {
        float s = bias[jl];
#pragma unroll
        for (int q = 0; q < 8; ++q) s += red[q][jl];
        out[(size_t)b * T_ + jl] = s;
    }
}

extern "C" void kernel_launch(void* const* d_in, const int* in_sizes, int n_in,
                              void* d_out, int out_size, void* d_ws, size_t ws_size,
                              hipStream_t stream) {
    const int*   ids       = (const int*)d_in[0];
    const float* embed     = (const float*)d_in[1];
    const float* in_proj_w = (const float*)d_in[2];
    const float* conv_w    = (const float*)d_in[3];
    const float* conv_b    = (const float*)d_in[4];
    const float* x_proj_w  = (const float*)d_in[5];
    const float* dt_w      = (const float*)d_in[6];
    const float* dt_b      = (const float*)d_in[7];
    const float* A_log     = (const float*)d_in[8];
    const float* D_p       = (const float*)d_in[9];
    const float* out_w     = (const float*)d_in[10];
    const float* norm_w    = (const float*)d_in[11];
    const float* norm_f_w  = (const float*)d_in[12];
    const float* top_w     = (const float*)d_in[13];
    const float* top_b     = (const float*)d_in[14];
    const float* bot_w     = (const float*)d_in[15];
    const float* bot_b     = (const float*)d_in[16];
    float* out = (float*)d_out;

    // workspace layout
    float* ws = (float*)d_ws;
    float* h    = ws;                         // 2048*768
    float* xz   = h + (size_t)BT_ * DM;       // 2048*3072
    float* proj = xz + (size_t)BT_ * 2 * E_;  // 2048*80
    float* dtT  = proj + (size_t)BT_ * PJ;    // 2048*1536 ([b][e][t])
    float* dxT  = dtT + (size_t)BT_ * E_;     // also reused as yzT (aliased on purpose)
    float* xdT  = dxT + (size_t)BT_ * E_;
    float* zsT  = xdT + (size_t)BT_ * E_;
    float* cls  = zsT + (size_t)BT_ * E_;     // 4*768
    float* hrel = cls + (size_t)B_ * DM;      // 4*1536
    unsigned short* us = (unsigned short*)(hrel + (size_t)B_ * H_);
    unsigned short* xi_h = us;                               // 2048*768
    unsigned short* xi_l = xi_h + (size_t)BT_ * DM;
    unsigned short* yz_h = xi_l + (size_t)BT_ * DM;          // 2048*1536
    unsigned short* yz_l = yz_h + (size_t)BT_ * E_;
    unsigned short* xc_h = yz_l + (size_t)BT_ * E_;          // 2048*1536
    unsigned short* xc_l = xc_h + (size_t)BT_ * E_;
    // all-layer weight splits
    unsigned short* wA_h = xc_l + (size_t)BT_ * E_;          // 4 x 3072x768
    unsigned short* wA_l = wA_h + (size_t)NL_ * 2 * E_ * DM;
    unsigned short* wB_h = wA_l + (size_t)NL_ * 2 * E_ * DM; // 4 x 768x1536
    unsigned short* wB_l = wB_h + (size_t)NL_ * DM * E_;
    unsigned short* wX_h = wB_l + (size_t)NL_ * DM * E_;     // 4 x 80x1536
    unsigned short* wX_l = wX_h + (size_t)NL_ * PJ * E_;
    float* pp  = (float*)(wX_l + (size_t)NL_ * PJ * E_);     // 4*2048*80 (x_proj partials)
    float* yzT = dxT;   // alias: safe (see k_scan3 comment)

    k_embed<<<BT_, 256, 0, stream>>>(ids, embed, h);
    // all-layer weight preprocessing (hoisted out of the layer loop)
    k_wsplit<<<dim3(2 * E_ / 32, DM / 32, NL_), 256, 0, stream>>>(
        in_proj_w, wA_h, wA_l, DM, 2 * E_);
    k_wsplit<<<dim3(DM / 32, E_ / 32, NL_), 256, 0, stream>>>(
        out_w, wB_h, wB_l, E_, DM);
    k_wsplitX<<<dim3(E_ / 16, 1, NL_), 256, 0, stream>>>(x_proj_w, wX_h, wX_l);

    for (int i = 0; i < NL_; ++i) {
        const float* cwi = conv_w + (size_t)i * E_ * K_;
        const float* cbi = conv_b + (size_t)i * E_;
        const float* dwi = dt_w + (size_t)i * R_ * E_;
        const float* dbi = dt_b + (size_t)i * E_;
        const float* ali = A_log + (size_t)i * E_ * N_;
        const float* dpi = D_p + (size_t)i * E_;
        const float* nwi = norm_w + (size_t)i * DM;
        unsigned short* wAh = wA_h + (size_t)i * 2 * E_ * DM;
        unsigned short* wAl = wA_l + (size_t)i * 2 * E_ * DM;
        unsigned short* wBh = wB_h + (size_t)i * DM * E_;
        unsigned short* wBl = wB_l + (size_t)i * DM * E_;
        unsigned short* wXh = wX_h + (size_t)i * PJ * E_;
        unsigned short* wXl = wX_l + (size_t)i * PJ * E_;

        k_rmsnorm<true><<<BT_, 256, 0, stream>>>(h, DM, nwi, nullptr, xi_h, xi_l);
        // xz = xi @ in_proj (MFMA bf16x2): 128x128 tile
        k_mmf<128, 128, 2, 2, false, 1><<<dim3(2 * E_ / 128, BT_ / 128), 256, 0, stream>>>(
            xi_h, xi_l, wAh, wAl, xz, BT_, 2 * E_, DM);
        k_conv<<<BT_ * E_ / 256, 256, 0, stream>>>(xz, cwi, cbi, xc_h, xc_l);
        // x_proj: proj[2048][80] = xc @ wX^T, K-split 4 + reduce
        k_mmf<128, PJ, 4, 1, false, 4><<<dim3(1, BT_ / 128, 4), 256, 0, stream>>>(
            xc_h, xc_l, wXh, wXl, pp, BT_, PJ, E_);
        k_padd<<<(BT_ * PJ + 255) / 256, 256, 0, stream>>>(pp, proj);
        k_prep<<<dim3(L_ / 64, E_ / 64, B_), 256, 0, stream>>>(
            proj, dwi, dbi, xc_h, xc_l, xz, dpi, dtT, dxT, xdT, zsT);
        k_scan3<<<B_ * E_, 256, 0, stream>>>(dtT, dxT, xdT, zsT, proj, ali, yzT);
        k_ytr<<<dim3(L_ / 64, E_ / 64, B_), 256, 0, stream>>>(yzT, yz_h, yz_l);
        // h += yz @ out_w: 64x64 tile, accumulate
        k_mmf<64, 64, 2, 2, true, 1><<<dim3(DM / 64, BT_ / 64), 256, 0, stream>>>(
            yz_h, yz_l, wBh, wBl, h, BT_, DM, E_);
    }

    k_rmsnorm<false><<<B_, 256, 0, stream>>>(h + (size_t)(L_ - 1) * DM, (long)L_ * DM,
                                             norm_f_w, cls, nullptr, nullptr);
    k_top<<<H_ / 64, 256, 0, stream>>>(cls, top_w, top_b, hrel);
    k_bot<<<B_, 256, 0, stream>>>(hrel, bot_w, bot_b, out);
}